// Round 11
// baseline (74.717 us; speedup 1.0000x reference)
//
#include <hip/hip_runtime.h>

// TemporalContrastiveLoss: B=512, T=256, D=256, temperature 0.1.
// Grid = 256 blocks (1/CU, 512 thr, launch_bounds(512,2)). 2 batches/block.
// S_raw = X*X^T over 8 chunks (64 cols each, 2 batches x 4).
// DEPTH-2 register prefetch at 64-col granularity: two 8-load sets ldA/ldB;
// set consumed at chunk g was issued at g-2 -> ~2 chunk-periods of latency
// cover, 16 KB/wave in flight. One lgkm-only barrier per chunk (vmcnt never
// drained in-loop). s_setprio(1) around MFMA cluster (T5).
// Epilogue per batch: inv=rsqrt(diag) from diagonal tiles, symmetric
// column-sum LSE (fixed max=10), super-diagonal target. K3: 512->1 mean.

typedef float f32x4  __attribute__((ext_vector_type(4)));
typedef float f32x16 __attribute__((ext_vector_type(16)));
typedef unsigned int u32x2 __attribute__((ext_vector_type(2)));
typedef unsigned int u32x4 __attribute__((ext_vector_type(4)));
typedef __bf16 bf16x8 __attribute__((ext_vector_type(8)));

#define NB 512
#define NT 256
#define ND 256
#define K10L2E 14.42695041f   // 10 * log2(e)

#define MFMA32 __builtin_amdgcn_mfma_f32_32x32x16_bf16

__device__ __forceinline__ unsigned int f2bf_rne(float f) {
  unsigned int u = __float_as_uint(f);
  return (u + 0x7fffu + ((u >> 16) & 1u)) >> 16;
}

// Barrier that does NOT drain vmcnt (prefetch stays in flight).
__device__ __forceinline__ void wg_barrier() {
  asm volatile("s_waitcnt lgkmcnt(0)" ::: "memory");
  __builtin_amdgcn_s_barrier();
  asm volatile("" ::: "memory");
}

__device__ __forceinline__ u32x2 pack_bf16x4(f32x4 v) {
  u32x2 o;
  o.x = f2bf_rne(v.x) | (f2bf_rne(v.y) << 16);
  o.y = f2bf_rne(v.z) | (f2bf_rne(v.w) << 16);
  return o;
}

// LDS chunk layout: [256 rows][8 slots of 16B], slot = c ^ (row&7)
// (byte ^= (row&7)<<4): spreads the stride-128B column reads across banks.
__global__ __launch_bounds__(512, 2) void fused_kernel(
    const float* __restrict__ x, float* __restrict__ partial) {
  __shared__ u32x4 ck[2][NT * 8];    // 2 x 32 KiB chunk double buffer
  __shared__ float invbuf[NT];       // 1/||x_r|| from MFMA diagonal
  __shared__ float sbuf[NT][5];      // per-col, per-64row-group sum exp(p-10)
  __shared__ float tbuf[NT];         // per-row target logit (x10, normalized)
  __shared__ float redbuf[8];

  const int t    = threadIdx.x;
  const int wave = t >> 6;
  const int lane = t & 63;
  const int lo5  = lane & 31;
  const int hi   = lane >> 5;
  const int sx6  = lo5 & 6;          // (lo5&7)&6
  const int hx   = hi ^ (lo5 & 1);

  // tile assignment: wave w -> tiles (tr, tcA), (tr, tcB); w<4 has diag in A
  const int d   = wave >> 2;
  const int tr  = wave & 3;
  const int tcA = (tr + d) & 3;
  const int tcB = (tr + d + 2) & 3;
  const int R = tr * 64, CA = tcA * 64, CB = tcB * 64;

  // frag base indices (u32x4 units, row stride 8)
  const int iA  = (R  + lo5) * 8;
  const int iBA = (CA + lo5) * 8;
  const int iBB = (CB + lo5) * 8;

  // staging: wave stages rows wave*32..+31 of each 64-col chunk
  const int lrow = lane >> 4;        // 0..3
  const int lcol = lane & 15;        // f32x4 index within 64 cols
  const int srow = wave * 32;

#define ISSUE(SET, TC) do {                                                  \
    const float* bp = x + ((size_t)blockIdx.x + (size_t)((TC) >> 2) * 256)   \
                          * (NT * ND) + ((TC) & 3) * 64;                     \
    _Pragma("unroll")                                                        \
    for (int i = 0; i < 8; ++i)                                              \
      SET[i] = *(const f32x4*)(bp + (srow + i * 4 + lrow) * ND + lcol * 4);  \
  } while (0)

#define CAST_WRITE(BUF, SET) do {                                            \
    _Pragma("unroll")                                                        \
    for (int i = 0; i < 8; ++i) {                                            \
      const int row = srow + i * 4 + lrow;                                   \
      const u32x2 o = pack_bf16x4(SET[i]);                                   \
      const int slot = (lcol >> 1) ^ (row & 7);                              \
      *(u32x2*)((unsigned int*)&ck[BUF][0]                                   \
                + (row * 32 + slot * 4 + (lcol & 1) * 2)) = o;               \
    }                                                                        \
  } while (0)

#define MFMA_CHUNK(BUF) do {                                                 \
    const u32x4* cb = &ck[BUF][0];                                           \
    __builtin_amdgcn_s_setprio(1);                                           \
    _Pragma("unroll")                                                        \
    for (int kb = 0; kb < 4; ++kb) {                                         \
      const int ko = ((kb * 2) ^ sx6) | hx;                                  \
      bf16x8 fa0  = __builtin_bit_cast(bf16x8, cb[iA  + ko]);                \
      bf16x8 fa1  = __builtin_bit_cast(bf16x8, cb[iA  + 256 + ko]);          \
      bf16x8 fbA0 = __builtin_bit_cast(bf16x8, cb[iBA + ko]);                \
      bf16x8 fbA1 = __builtin_bit_cast(bf16x8, cb[iBA + 256 + ko]);          \
      bf16x8 fbB0 = __builtin_bit_cast(bf16x8, cb[iBB + ko]);                \
      bf16x8 fbB1 = __builtin_bit_cast(bf16x8, cb[iBB + 256 + ko]);          \
      aA0 = MFMA32(fa0, fbA0, aA0, 0, 0, 0);                                 \
      aA1 = MFMA32(fa0, fbA1, aA1, 0, 0, 0);                                 \
      aA2 = MFMA32(fa1, fbA0, aA2, 0, 0, 0);                                 \
      aA3 = MFMA32(fa1, fbA1, aA3, 0, 0, 0);                                 \
      aB0 = MFMA32(fa0, fbB0, aB0, 0, 0, 0);                                 \
      aB1 = MFMA32(fa0, fbB1, aB1, 0, 0, 0);                                 \
      aB2 = MFMA32(fa1, fbB0, aB2, 0, 0, 0);                                 \
      aB3 = MFMA32(fa1, fbB1, aB3, 0, 0, 0);                                 \
    }                                                                        \
    __builtin_amdgcn_s_setprio(0);                                           \
  } while (0)

  f32x16 aA0, aA1, aA2, aA3, aB0, aB1, aB2, aB3;
#pragma unroll
  for (int e = 0; e < 16; ++e) {
    aA0[e] = 0.f; aA1[e] = 0.f; aA2[e] = 0.f; aA3[e] = 0.f;
    aB0[e] = 0.f; aB1[e] = 0.f; aB2[e] = 0.f; aB3[e] = 0.f;
  }

  f32x4 ldA[8], ldB[8];
  ISSUE(ldA, 0);
  ISSUE(ldB, 1);

#pragma unroll 1
  for (int g = 0; g < 8; g += 2) {
    // ---- even chunk g: consume ldA, buf0 ----
    CAST_WRITE(0, ldA);
    if (g + 2 < 8) ISSUE(ldA, g + 2);    // lands 2 chunk-periods later
    wg_barrier();
    MFMA_CHUNK(0);

    // ---- odd chunk g+1: consume ldB, buf1 ----
    CAST_WRITE(1, ldB);
    if (g + 3 < 8) ISSUE(ldB, g + 3);
    wg_barrier();
    MFMA_CHUNK(1);

    // ---- batch epilogue after chunk 3 (batch 0) and chunk 7 (batch 1) ----
    if ((g & 2) != 0) {                  // g == 2 or g == 6
      const int bb = (int)blockIdx.x + (g >> 2) * 256;

      // diagonal tiles (waves 0-3, tile A): publish inv = rsqrt(diag)
      if (d == 0) {
        float dv0 = 1.0f, dv1 = 1.0f;
#pragma unroll
        for (int rg = 0; rg < 16; ++rg) {
          const int rowe = (rg & 3) + 8 * (rg >> 2) + 4 * hi;
          if (rowe == lo5) { dv0 = aA0[rg]; dv1 = aA3[rg]; }
        }
        if (hi == ((lo5 >> 2) & 1)) {
          invbuf[R + lo5]      = rsqrtf(fmaxf(dv0, 1e-24f));
          invbuf[R + 32 + lo5] = rsqrtf(fmaxf(dv1, 1e-24f));
        }
      }
      wg_barrier();   // invbuf valid; next-batch prefetch stays in flight

      // scaled exp column-sums (S symmetric: row-LSE sum == column sum)
      {
        const float ic0 = invbuf[CA + lo5] * K10L2E;
        const float ic1 = invbuf[CA + 32 + lo5] * K10L2E;
        float e0 = 0.f, e1 = 0.f;
#pragma unroll
        for (int rg = 0; rg < 16; ++rg) {
          const int rowe = (rg & 3) + 8 * (rg >> 2) + 4 * hi;
          const float ir0 = invbuf[R + rowe], ir1 = invbuf[R + 32 + rowe];
          e0 += exp2f(fmaf(aA0[rg] * ir0, ic0, -K10L2E));
          e0 += exp2f(fmaf(aA2[rg] * ir1, ic0, -K10L2E));
          e1 += exp2f(fmaf(aA1[rg] * ir0, ic1, -K10L2E));
          e1 += exp2f(fmaf(aA3[rg] * ir1, ic1, -K10L2E));
        }
        e0 += __shfl_xor(e0, 32);
        e1 += __shfl_xor(e1, 32);
        if (hi == 0) sbuf[CA + lo5][tr] = e0;
        else         sbuf[CA + 32 + lo5][tr] = e1;
      }
      {
        const float ic0 = invbuf[CB + lo5] * K10L2E;
        const float ic1 = invbuf[CB + 32 + lo5] * K10L2E;
        float e0 = 0.f, e1 = 0.f;
#pragma unroll
        for (int rg = 0; rg < 16; ++rg) {
          const int rowe = (rg & 3) + 8 * (rg >> 2) + 4 * hi;
          const float ir0 = invbuf[R + rowe], ir1 = invbuf[R + 32 + rowe];
          e0 += exp2f(fmaf(aB0[rg] * ir0, ic0, -K10L2E));
          e0 += exp2f(fmaf(aB2[rg] * ir1, ic0, -K10L2E));
          e1 += exp2f(fmaf(aB1[rg] * ir0, ic1, -K10L2E));
          e1 += exp2f(fmaf(aB3[rg] * ir1, ic1, -K10L2E));
        }
        e0 += __shfl_xor(e0, 32);
        e1 += __shfl_xor(e1, 32);
        if (hi == 0) sbuf[CB + lo5][tr] = e0;
        else         sbuf[CB + 32 + lo5][tr] = e1;
      }

      // super-diagonal target (tiles with tcA==tr or tcA==tr+1)
      if (tcA == tr || tcA == tr + 1) {
#pragma unroll
        for (int ar = 0; ar < 2; ++ar) {
#pragma unroll
          for (int rg = 0; rg < 16; ++rg) {
            const int r = R + ar * 32 + (rg & 3) + 8 * (rg >> 2) + 4 * hi;
            const int tcol = r + 1 - CA;
            if (r < NT - 1 && tcol >= 0 && tcol < 64 && lo5 == (tcol & 31)) {
              const float v = (tcol < 32) ? (ar ? aA2[rg] : aA0[rg])
                                          : (ar ? aA3[rg] : aA1[rg]);
              tbuf[r] = 10.0f * v * invbuf[r] * invbuf[r + 1];
            }
          }
        }
      }
      wg_barrier();   // sbuf/tbuf complete

      // merge 4 row-groups per column, subtract target, block-reduce
      float val = 0.0f;
      if (t < NT - 1) {
        const float s = sbuf[t][0] + sbuf[t][1] + sbuf[t][2] + sbuf[t][3];
        val = 10.0f + __logf(s) - tbuf[t];
      }
#pragma unroll
      for (int dd = 1; dd < 64; dd <<= 1) val += __shfl_xor(val, dd);
      if (lane == 0) redbuf[wave] = val;
      wg_barrier();
      if (t == 0) {
        float s = 0.f;
#pragma unroll
        for (int w = 0; w < 8; ++w) s += redbuf[w];
        partial[bb] = s;
      }

      // reset accumulators for next batch
#pragma unroll
      for (int e = 0; e < 16; ++e) {
        aA0[e] = 0.f; aA1[e] = 0.f; aA2[e] = 0.f; aA3[e] = 0.f;
        aB0[e] = 0.f; aB1[e] = 0.f; aB2[e] = 0.f; aB3[e] = 0.f;
      }
    }
  }
#undef ISSUE
#undef CAST_WRITE
#undef MFMA_CHUNK
}

// ---------------- K3: 512 partials -> mean (deterministic) ----------------
__global__ __launch_bounds__(256) void reduce_kernel(
    const float* __restrict__ partial, float* __restrict__ out) {
  const int t = threadIdx.x;
  float v = partial[t] + partial[t + 256];
#pragma unroll
  for (int d = 1; d < 64; d <<= 1) v += __shfl_xor(v, d);
  __shared__ float red[4];
  if ((t & 63) == 0) red[t >> 6] = v;
  __syncthreads();
  if (t == 0)
    out[0] = (red[0] + red[1] + red[2] + red[3]) * (1.0f / (float)(NB * (NT - 1)));
}

extern "C" void kernel_launch(void* const* d_in, const int* in_sizes, int n_in,
                              void* d_out, int out_size, void* d_ws, size_t ws_size,
                              hipStream_t stream) {
  (void)in_sizes; (void)n_in; (void)out_size; (void)ws_size;
  const float* x = (const float*)d_in[0];
  float* out = (float*)d_out;
  float* partial = (float*)d_ws;   // 2 KiB

  hipLaunchKernelGGL(fused_kernel, dim3(NB / 2), dim3(512), 0, stream, x, partial);
  hipLaunchKernelGGL(reduce_kernel, dim3(1), dim3(256), 0, stream, partial, out);
}

// Round 12
// 45.526 us; speedup vs baseline: 1.6412x; 1.6412x over previous
//
#include <hip/hip_runtime.h>

// TemporalContrastiveLoss: B=512, T=256, D=256, temperature 0.1.
// Grid = 256 blocks (1/CU, 512 thr, launch_bounds(512,2)). 2 batches/block.
// S_raw = X*X^T over 16 sub-chunks (32 cols, 2 batches x 8), depth-2
// register prefetch (ldA[4]/ldB[4], 32 VGPR -- proven no-spill).
// TRANSPOSE-PAIR tile map: wave w<6 owns tiles (gA,gB)+(gB,gA) (frag pair
// shared: 4 ds_read_b128 per 8 MFMAs, -33% LDS reads); waves 6,7 own the
// 4 diagonal tiles (also 4 reads / 8 MFMAs) and publish inv=rsqrt(diag).
// lgkm-only barriers (vmcnt never drained in-loop). Symmetric column-sum
// LSE (fixed max=10), super-diagonal target. K3: 512->1 mean.

typedef float f32x4  __attribute__((ext_vector_type(4)));
typedef float f32x16 __attribute__((ext_vector_type(16)));
typedef unsigned int u32x2 __attribute__((ext_vector_type(2)));
typedef unsigned int u32x4 __attribute__((ext_vector_type(4)));
typedef __bf16 bf16x8 __attribute__((ext_vector_type(8)));

#define NB 512
#define NT 256
#define ND 256
#define K10L2E 14.42695041f   // 10 * log2(e)

#define MFMA32 __builtin_amdgcn_mfma_f32_32x32x16_bf16

__device__ __forceinline__ unsigned int f2bf_rne(float f) {
  unsigned int u = __float_as_uint(f);
  return (u + 0x7fffu + ((u >> 16) & 1u)) >> 16;
}

// Barrier that does NOT drain vmcnt (prefetch stays in flight).
__device__ __forceinline__ void wg_barrier() {
  asm volatile("s_waitcnt lgkmcnt(0)" ::: "memory");
  __builtin_amdgcn_s_barrier();
  asm volatile("" ::: "memory");
}

__device__ __forceinline__ u32x2 pack_bf16x4(f32x4 v) {
  u32x2 o;
  o.x = f2bf_rne(v.x) | (f2bf_rne(v.y) << 16);
  o.y = f2bf_rne(v.z) | (f2bf_rne(v.w) << 16);
  return o;
}

// LDS sub-chunk layout (32 cols, 16 KiB): [128 double-rows][8 slot16 of 16B],
// row r, logical 8-col slot s: slot16 = ((r&1)*4 + s) ^ ((r>>1)&7)
// -> ds_read_b128 frags and ds_write_b64 staging both <=2-way (free).
__global__ __launch_bounds__(512, 2) void fused_kernel(
    const float* __restrict__ x, float* __restrict__ partial) {
  __shared__ u32x4 ck[2][128 * 8];   // 2 x 16 KiB sub-chunk double buffer
  __shared__ float invbuf[NT];       // 1/||x_r|| from MFMA diagonal
  __shared__ float sbuf[NT][5];      // per-col, per-64row-group sum exp(p-10)
  __shared__ float tbuf[NT];         // per-row target logit (x10, normalized)
  __shared__ float redbuf[8];

  const int t    = threadIdx.x;
  const int wave = t >> 6;
  const int lane = t & 63;
  const int lo5  = lane & 31;
  const int hi   = lane >> 5;
  const int sxd  = (lo5 >> 1) & 7;   // frag-read row-derived xor
  const int sx4  = (lo5 & 1) * 4;

  // transpose-pair tile assignment:
  //  wave: 0:(0,1)+(1,0) 1:(0,2)+(2,0) 2:(0,3)+(3,0) 3:(1,2)+(2,1)
  //        4:(1,3)+(3,1) 5:(2,3)+(3,2) 6:(0,0)+(1,1) 7:(2,2)+(3,3)
  const int gA = (0x20211000u >> (wave * 4)) & 0xF;
  const int gB = (0x31332321u >> (wave * 4)) & 0xF;
  const bool isPair = (wave < 6);
  const int u0 = gA, v0 = isPair ? gB : gA;   // tile 0 = (u0 rows, v0 cols)
  const int u1 = gB, v1 = isPair ? gA : gB;   // tile 1 = (u1 rows, v1 cols)

  // frag base indices (u32x4 units): rows group*64+lo5; +32 rows => +128
  const int iXA = ((gA * 64 + lo5) >> 1) * 8;
  const int iXB = ((gB * 64 + lo5) >> 1) * 8;

  // staging: wave stages rows wave*32..+31 of each 32-col sub-chunk
  const int j8   = lane >> 3;        // 0..7
  const int c8   = lane & 7;         // 16B (4-fp32) index within 32 cols
  const int s_   = c8 >> 1;          // logical 8-col slot
  const int half = c8 & 1;           // 8B half within slot
  const int srow = wave * 32;

#define ISSUE(SET, TC) do {                                                  \
    const float* bp = x + ((size_t)blockIdx.x + (size_t)((TC) >> 3) * 256)   \
                          * (NT * ND) + ((TC) & 7) * 32;                     \
    _Pragma("unroll")                                                        \
    for (int i = 0; i < 4; ++i)                                              \
      SET[i] = *(const f32x4*)(bp + (srow + i * 8 + j8) * ND + c8 * 4);      \
  } while (0)

#define CAST_WRITE(BUF, SET) do {                                            \
    _Pragma("unroll")                                                        \
    for (int i = 0; i < 4; ++i) {                                            \
      const int r = srow + i * 8 + j8;                                       \
      const u32x2 o = pack_bf16x4(SET[i]);                                   \
      const int slot16 = ((r & 1) * 4 + s_) ^ ((r >> 1) & 7);                \
      *(u32x2*)((unsigned int*)&ck[BUF][0]                                   \
                + ((r >> 1) * 32 + slot16 * 4 + half * 2)) = o;              \
    }                                                                        \
  } while (0)

#define MFMA_CHUNK(BUF) do {                                                 \
    const u32x4* cb = &ck[BUF][0];                                           \
    _Pragma("unroll")                                                        \
    for (int kb = 0; kb < 2; ++kb) {                                         \
      const int ko = (sx4 + kb * 2 + hi) ^ sxd;                              \
      bf16x8 xa0 = __builtin_bit_cast(bf16x8, cb[iXA + ko]);                 \
      bf16x8 xa1 = __builtin_bit_cast(bf16x8, cb[iXA + 128 + ko]);           \
      bf16x8 xb0 = __builtin_bit_cast(bf16x8, cb[iXB + ko]);                 \
      bf16x8 xb1 = __builtin_bit_cast(bf16x8, cb[iXB + 128 + ko]);           \
      if (isPair) {                                                          \
        t0a0 = MFMA32(xa0, xb0, t0a0, 0, 0, 0);   /* (gA,gB) */              \
        t0a1 = MFMA32(xa0, xb1, t0a1, 0, 0, 0);                              \
        t0a2 = MFMA32(xa1, xb0, t0a2, 0, 0, 0);                              \
        t0a3 = MFMA32(xa1, xb1, t0a3, 0, 0, 0);                              \
        t1a0 = MFMA32(xb0, xa0, t1a0, 0, 0, 0);   /* (gB,gA) */              \
        t1a1 = MFMA32(xb0, xa1, t1a1, 0, 0, 0);                              \
        t1a2 = MFMA32(xb1, xa0, t1a2, 0, 0, 0);                              \
        t1a3 = MFMA32(xb1, xa1, t1a3, 0, 0, 0);                              \
      } else {                                                               \
        t0a0 = MFMA32(xa0, xa0, t0a0, 0, 0, 0);   /* (gA,gA) */              \
        t0a1 = MFMA32(xa0, xa1, t0a1, 0, 0, 0);                              \
        t0a2 = MFMA32(xa1, xa0, t0a2, 0, 0, 0);                              \
        t0a3 = MFMA32(xa1, xa1, t0a3, 0, 0, 0);                              \
        t1a0 = MFMA32(xb0, xb0, t1a0, 0, 0, 0);   /* (gB,gB) */              \
        t1a1 = MFMA32(xb0, xb1, t1a1, 0, 0, 0);                              \
        t1a2 = MFMA32(xb1, xb0, t1a2, 0, 0, 0);                              \
        t1a3 = MFMA32(xb1, xb1, t1a3, 0, 0, 0);                              \
      }                                                                      \
    }                                                                        \
  } while (0)

// generic per-tile (U rows-group, V cols-group) epilogue pieces
#define EPI_TILE(U, V, A0, A1, A2, A3) do {                                  \
    const float ic0 = invbuf[(V) * 64 + lo5] * K10L2E;                       \
    const float ic1 = invbuf[(V) * 64 + 32 + lo5] * K10L2E;                  \
    float e0 = 0.f, e1 = 0.f;                                                \
    _Pragma("unroll")                                                        \
    for (int rg = 0; rg < 16; ++rg) {                                        \
      const int rowe = (rg & 3) + 8 * (rg >> 2) + 4 * hi;                    \
      const float ir0 = invbuf[(U) * 64 + rowe];                             \
      const float ir1 = invbuf[(U) * 64 + 32 + rowe];                        \
      e0 += exp2f(fmaf(A0[rg] * ir0, ic0, -K10L2E));                         \
      e0 += exp2f(fmaf(A2[rg] * ir1, ic0, -K10L2E));                         \
      e1 += exp2f(fmaf(A1[rg] * ir0, ic1, -K10L2E));                         \
      e1 += exp2f(fmaf(A3[rg] * ir1, ic1, -K10L2E));                         \
    }                                                                        \
    e0 += __shfl_xor(e0, 32);                                                \
    e1 += __shfl_xor(e1, 32);                                                \
    if (hi == 0) sbuf[(V) * 64 + lo5][U] = e0;                               \
    else         sbuf[(V) * 64 + 32 + lo5][U] = e1;                          \
  } while (0)

#define TGT_TILE(U, V, A0, A1, A2, A3) do {                                  \
    if ((V) == (U) || (V) == (U) + 1) {                                      \
      _Pragma("unroll")                                                      \
      for (int ar = 0; ar < 2; ++ar) {                                       \
        _Pragma("unroll")                                                    \
        for (int rg = 0; rg < 16; ++rg) {                                    \
          const int r = (U) * 64 + ar * 32 + (rg & 3) + 8 * (rg >> 2) + 4 * hi; \
          const int tcol = r + 1 - (V) * 64;                                 \
          if (r < NT - 1 && tcol >= 0 && tcol < 64 && lo5 == (tcol & 31)) {  \
            const float v = (tcol < 32) ? (ar ? A2[rg] : A0[rg])             \
                                        : (ar ? A3[rg] : A1[rg]);            \
            tbuf[r] = 10.0f * v * invbuf[r] * invbuf[r + 1];                 \
          }                                                                  \
        }                                                                    \
      }                                                                      \
    }                                                                        \
  } while (0)

#define DIAG_TILE(G, A0, A3) do {                                            \
    float dv0 = 1.0f, dv1 = 1.0f;                                            \
    _Pragma("unroll")                                                        \
    for (int rg = 0; rg < 16; ++rg) {                                        \
      const int rowe = (rg & 3) + 8 * (rg >> 2) + 4 * hi;                    \
      if (rowe == lo5) { dv0 = A0[rg]; dv1 = A3[rg]; }                       \
    }                                                                        \
    if (hi == ((lo5 >> 2) & 1)) {                                            \
      invbuf[(G) * 64 + lo5]      = rsqrtf(fmaxf(dv0, 1e-24f));              \
      invbuf[(G) * 64 + 32 + lo5] = rsqrtf(fmaxf(dv1, 1e-24f));              \
    }                                                                        \
  } while (0)

  f32x16 t0a0, t0a1, t0a2, t0a3, t1a0, t1a1, t1a2, t1a3;
#pragma unroll
  for (int e = 0; e < 16; ++e) {
    t0a0[e] = 0.f; t0a1[e] = 0.f; t0a2[e] = 0.f; t0a3[e] = 0.f;
    t1a0[e] = 0.f; t1a1[e] = 0.f; t1a2[e] = 0.f; t1a3[e] = 0.f;
  }

  f32x4 ldA[4], ldB[4];
  ISSUE(ldA, 0);
  ISSUE(ldB, 1);

#pragma unroll 1
  for (int g = 0; g < 16; g += 2) {
    // ---- even sub-chunk g: consume ldA, buf0 ----
    CAST_WRITE(0, ldA);
    if (g + 2 < 16) ISSUE(ldA, g + 2);   // lands ~2 sub-chunk periods later
    wg_barrier();
    MFMA_CHUNK(0);

    // ---- odd sub-chunk g+1: consume ldB, buf1 ----
    CAST_WRITE(1, ldB);
    if (g + 3 < 16) ISSUE(ldB, g + 3);
    wg_barrier();
    MFMA_CHUNK(1);

    // ---- batch epilogue at g+1 == 7 (batch 0) and 15 (batch 1) ----
    if (((g + 1) & 7) == 7) {
      const int bb = (int)blockIdx.x + ((g + 1) >> 3) * 256;

      // diagonal waves publish inv = rsqrt(diag) for all 4 row-groups
      if (!isPair) {
        DIAG_TILE(gA, t0a0, t0a3);
        DIAG_TILE(gB, t1a0, t1a3);
      }
      wg_barrier();   // invbuf valid; next-batch prefetch stays in flight

      // scaled exp column-sums (S symmetric: row-LSE sum == column sum)
      EPI_TILE(u0, v0, t0a0, t0a1, t0a2, t0a3);
      EPI_TILE(u1, v1, t1a0, t1a1, t1a2, t1a3);

      // super-diagonal targets (diag tiles + (g,g+1) pair tiles)
      TGT_TILE(u0, v0, t0a0, t0a1, t0a2, t0a3);
      TGT_TILE(u1, v1, t1a0, t1a1, t1a2, t1a3);
      wg_barrier();   // sbuf/tbuf complete

      // merge 4 row-groups per column, subtract target, block-reduce
      float val = 0.0f;
      if (t < NT - 1) {
        const float s = sbuf[t][0] + sbuf[t][1] + sbuf[t][2] + sbuf[t][3];
        val = 10.0f + __logf(s) - tbuf[t];
      }
#pragma unroll
      for (int dd = 1; dd < 64; dd <<= 1) val += __shfl_xor(val, dd);
      if (lane == 0) redbuf[wave] = val;
      wg_barrier();
      if (t == 0) {
        float s = 0.f;
#pragma unroll
        for (int w = 0; w < 8; ++w) s += redbuf[w];
        partial[bb] = s;
      }

      // reset accumulators for next batch
#pragma unroll
      for (int e = 0; e < 16; ++e) {
        t0a0[e] = 0.f; t0a1[e] = 0.f; t0a2[e] = 0.f; t0a3[e] = 0.f;
        t1a0[e] = 0.f; t1a1[e] = 0.f; t1a2[e] = 0.f; t1a3[e] = 0.f;
      }
    }
  }
#undef ISSUE
#undef CAST_WRITE
#undef MFMA_CHUNK
#undef EPI_TILE
#undef TGT_TILE
#undef DIAG_TILE
}

// ---------------- K3: 512 partials -> mean (deterministic) ----------------
__global__ __launch_bounds__(256) void reduce_kernel(
    const float* __restrict__ partial, float* __restrict__ out) {
  const int t = threadIdx.x;
  float v = partial[t] + partial[t + 256];
#pragma unroll
  for (int d = 1; d < 64; d <<= 1) v += __shfl_xor(v, d);
  __shared__ float red[4];
  if ((t & 63) == 0) red[t >> 6] = v;
  __syncthreads();
  if (t == 0)
    out[0] = (red[0] + red[1] + red[2] + red[3]) * (1.0f / (float)(NB * (NT - 1)));
}

extern "C" void kernel_launch(void* const* d_in, const int* in_sizes, int n_in,
                              void* d_out, int out_size, void* d_ws, size_t ws_size,
                              hipStream_t stream) {
  (void)in_sizes; (void)n_in; (void)out_size; (void)ws_size;
  const float* x = (const float*)d_in[0];
  float* out = (float*)d_out;
  float* partial = (float*)d_ws;   // 2 KiB

  hipLaunchKernelGGL(fused_kernel, dim3(NB / 2), dim3(512), 0, stream, x, partial);
  hipLaunchKernelGGL(reduce_kernel, dim3(1), dim3(256), 0, stream, partial, out);
}

// Round 13
// 41.853 us; speedup vs baseline: 1.7852x; 1.0878x over previous
//
#include <hip/hip_runtime.h>

// TemporalContrastiveLoss: B=512, T=256, D=256, temperature 0.1.
// Grid = 256 blocks (1/CU), 1024 THREADS (16 waves, 4/SIMD -- double TLP:
// acc = 64 VGPR/thread at 1 tile/wave, fits the 128-reg cap of (1024,4)).
// 2 batches/block; S_raw = X*X^T over 16 sub-chunks (32 cols each).
// Depth-2 register prefetch (ldA[2]/ldB[2], 16 VGPR); lgkm-only barriers
// (vmcnt never drained in-loop). Wave (tr,tc)=(w>>2,w&3) owns one 64x64
// tile: 4 ds_read_b128 + 4 MFMA per kb, uniform code (no branches).
// Diag waves (tr==tc) publish inv=rsqrt(diag); symmetric column-sum LSE
// (fixed max=10); super-diagonal target. K3: 512->1 mean.

typedef float f32x4  __attribute__((ext_vector_type(4)));
typedef float f32x16 __attribute__((ext_vector_type(16)));
typedef unsigned int u32x2 __attribute__((ext_vector_type(2)));
typedef unsigned int u32x4 __attribute__((ext_vector_type(4)));
typedef __bf16 bf16x8 __attribute__((ext_vector_type(8)));

#define NB 512
#define NT 256
#define ND 256
#define K10L2E 14.42695041f   // 10 * log2(e)

#define MFMA32 __builtin_amdgcn_mfma_f32_32x32x16_bf16

__device__ __forceinline__ unsigned int f2bf_rne(float f) {
  unsigned int u = __float_as_uint(f);
  return (u + 0x7fffu + ((u >> 16) & 1u)) >> 16;
}

// Barrier that does NOT drain vmcnt (prefetch stays in flight).
__device__ __forceinline__ void wg_barrier() {
  asm volatile("s_waitcnt lgkmcnt(0)" ::: "memory");
  __builtin_amdgcn_s_barrier();
  asm volatile("" ::: "memory");
}

__device__ __forceinline__ u32x2 pack_bf16x4(f32x4 v) {
  u32x2 o;
  o.x = f2bf_rne(v.x) | (f2bf_rne(v.y) << 16);
  o.y = f2bf_rne(v.z) | (f2bf_rne(v.w) << 16);
  return o;
}

// LDS sub-chunk layout (32 cols, 16 KiB): [128 double-rows][8 slot16 of 16B],
// row r, 16B piece p (cols p*8..+8 bf16): slot16 = ((r&1)*4 + p) ^ ((r>>1)&7)
// -> ds_read_b128 frags and ds_write_b64 staging both <=2-way (free).
__global__ __launch_bounds__(1024, 4) void fused_kernel(
    const float* __restrict__ x, float* __restrict__ partial) {
  __shared__ u32x4 ck[2][128 * 8];   // 2 x 16 KiB sub-chunk double buffer
  __shared__ float invbuf[NT];       // 1/||x_r|| from MFMA diagonal
  __shared__ float sbuf[NT][5];      // per-col, per-64row-group sum exp(p-10)
  __shared__ float tbuf[NT];         // per-row target logit (x10, normalized)
  __shared__ float redbuf[16];

  const int t    = threadIdx.x;
  const int wave = t >> 6;
  const int lane = t & 63;
  const int lo5  = lane & 31;
  const int hi   = lane >> 5;
  const int sxd  = (lo5 >> 1) & 7;   // frag-read row-derived xor
  const int sx4  = (lo5 & 1) * 4;

  // one 64x64 tile per wave: (tr rows-group, tc cols-group)
  const int tr = wave >> 2;
  const int tc = wave & 3;
  const int R = tr * 64, C = tc * 64;

  // frag base indices (u32x4 units); +32 rows => +128
  const int iA = ((R + lo5) >> 1) * 8;
  const int iB = ((C + lo5) >> 1) * 8;

  // staging: wave stages rows wave*16..+15 of each 32-col sub-chunk;
  // lane: row srow+(lane>>2), f32x4 chunks qa and qa+4 (cols chunk*4..+4)
  const int srow = wave * 16;
  const int rrow = srow + (lane >> 2);
  const int qa   = lane & 3;

#define ISSUE(SET, TC) do {                                                  \
    const float* bp = x + ((size_t)blockIdx.x + (size_t)((TC) >> 3) * 256)   \
                          * (NT * ND) + ((TC) & 7) * 32;                     \
    SET[0] = *(const f32x4*)(bp + rrow * ND + qa * 4);                       \
    SET[1] = *(const f32x4*)(bp + rrow * ND + (qa + 4) * 4);                 \
  } while (0)

#define CAST_WRITE(BUF, SET) do {                                            \
    _Pragma("unroll")                                                        \
    for (int i = 0; i < 2; ++i) {                                            \
      const int c = qa + i * 4;                                              \
      const u32x2 o = pack_bf16x4(SET[i]);                                   \
      const int s = c >> 1, half = c & 1;                                    \
      const int slot16 = ((rrow & 1) * 4 + s) ^ ((rrow >> 1) & 7);           \
      *(u32x2*)((unsigned int*)&ck[BUF][0]                                   \
                + ((rrow >> 1) * 32 + slot16 * 4 + half * 2)) = o;           \
    }                                                                        \
  } while (0)

#define MFMA_CHUNK(BUF) do {                                                 \
    const u32x4* cb = &ck[BUF][0];                                           \
    _Pragma("unroll")                                                        \
    for (int kb = 0; kb < 2; ++kb) {                                         \
      const int ko = (sx4 + kb * 2 + hi) ^ sxd;                              \
      bf16x8 fa0 = __builtin_bit_cast(bf16x8, cb[iA + ko]);                  \
      bf16x8 fa1 = __builtin_bit_cast(bf16x8, cb[iA + 128 + ko]);            \
      bf16x8 fb0 = __builtin_bit_cast(bf16x8, cb[iB + ko]);                  \
      bf16x8 fb1 = __builtin_bit_cast(bf16x8, cb[iB + 128 + ko]);            \
      a0 = MFMA32(fa0, fb0, a0, 0, 0, 0);                                    \
      a1 = MFMA32(fa0, fb1, a1, 0, 0, 0);                                    \
      a2 = MFMA32(fa1, fb0, a2, 0, 0, 0);                                    \
      a3 = MFMA32(fa1, fb1, a3, 0, 0, 0);                                    \
    }                                                                        \
  } while (0)

  f32x16 a0, a1, a2, a3;
#pragma unroll
  for (int e = 0; e < 16; ++e) { a0[e] = 0.f; a1[e] = 0.f; a2[e] = 0.f; a3[e] = 0.f; }

  f32x4 ldA[2], ldB[2];
  ISSUE(ldA, 0);
  ISSUE(ldB, 1);

#pragma unroll 1
  for (int g = 0; g < 16; g += 2) {
    // ---- even sub-chunk g: consume ldA, buf0 ----
    CAST_WRITE(0, ldA);
    if (g + 2 < 16) ISSUE(ldA, g + 2);   // lands ~2 sub-chunk periods later
    wg_barrier();
    MFMA_CHUNK(0);

    // ---- odd sub-chunk g+1: consume ldB, buf1 ----
    CAST_WRITE(1, ldB);
    if (g + 3 < 16) ISSUE(ldB, g + 3);
    wg_barrier();
    MFMA_CHUNK(1);

    // ---- batch epilogue at g+1 == 7 (batch 0) and 15 (batch 1) ----
    if (((g + 1) & 7) == 7) {
      const int bb = (int)blockIdx.x + ((g + 1) >> 3) * 256;

      // diagonal waves (tr==tc) publish inv = rsqrt(diag)
      if (tr == tc) {
        float dv0 = 1.0f, dv1 = 1.0f;
#pragma unroll
        for (int rg = 0; rg < 16; ++rg) {
          const int rowe = (rg & 3) + 8 * (rg >> 2) + 4 * hi;
          if (rowe == lo5) { dv0 = a0[rg]; dv1 = a3[rg]; }
        }
        if (hi == ((lo5 >> 2) & 1)) {
          invbuf[R + lo5]      = rsqrtf(fmaxf(dv0, 1e-24f));
          invbuf[R + 32 + lo5] = rsqrtf(fmaxf(dv1, 1e-24f));
        }
      }
      wg_barrier();   // invbuf valid; next-batch prefetch stays in flight

      // scaled exp column-sums (S symmetric: row-LSE sum == column sum)
      {
        const float ic0 = invbuf[C + lo5] * K10L2E;
        const float ic1 = invbuf[C + 32 + lo5] * K10L2E;
        float e0 = 0.f, e1 = 0.f;
#pragma unroll
        for (int rg = 0; rg < 16; ++rg) {
          const int rowe = (rg & 3) + 8 * (rg >> 2) + 4 * hi;
          const float ir0 = invbuf[R + rowe], ir1 = invbuf[R + 32 + rowe];
          e0 += exp2f(fmaf(a0[rg] * ir0, ic0, -K10L2E));
          e0 += exp2f(fmaf(a2[rg] * ir1, ic0, -K10L2E));
          e1 += exp2f(fmaf(a1[rg] * ir0, ic1, -K10L2E));
          e1 += exp2f(fmaf(a3[rg] * ir1, ic1, -K10L2E));
        }
        e0 += __shfl_xor(e0, 32);
        e1 += __shfl_xor(e1, 32);
        if (hi == 0) sbuf[C + lo5][tr] = e0;
        else         sbuf[C + 32 + lo5][tr] = e1;
      }

      // super-diagonal target (tiles with tc==tr or tc==tr+1)
      if (tc == tr || tc == tr + 1) {
#pragma unroll
        for (int ar = 0; ar < 2; ++ar) {
#pragma unroll
          for (int rg = 0; rg < 16; ++rg) {
            const int r = R + ar * 32 + (rg & 3) + 8 * (rg >> 2) + 4 * hi;
            const int tcol = r + 1 - C;
            if (r < NT - 1 && tcol >= 0 && tcol < 64 && lo5 == (tcol & 31)) {
              const float v = (tcol < 32) ? (ar ? a2[rg] : a0[rg])
                                          : (ar ? a3[rg] : a1[rg]);
              tbuf[r] = 10.0f * v * invbuf[r] * invbuf[r + 1];
            }
          }
        }
      }
      wg_barrier();   // sbuf/tbuf complete

      // merge 4 row-groups per column, subtract target, block-reduce
      float val = 0.0f;
      if (t < NT - 1) {
        const float s = sbuf[t][0] + sbuf[t][1] + sbuf[t][2] + sbuf[t][3];
        val = 10.0f + __logf(s) - tbuf[t];
      }
#pragma unroll
      for (int dd = 1; dd < 64; dd <<= 1) val += __shfl_xor(val, dd);
      if (lane == 0) redbuf[wave] = val;
      wg_barrier();
      if (t == 0) {
        float s = 0.f;
#pragma unroll
        for (int w = 0; w < 16; ++w) s += redbuf[w];
        partial[bb] = s;
      }

      // reset accumulators for next batch
#pragma unroll
      for (int e = 0; e < 16; ++e) { a0[e] = 0.f; a1[e] = 0.f; a2[e] = 0.f; a3[e] = 0.f; }
    }
  }
#undef ISSUE
#undef CAST_WRITE
#undef MFMA_CHUNK
}

// ---------------- K3: 512 partials -> mean (deterministic) ----------------
__global__ __launch_bounds__(256) void reduce_kernel(
    const float* __restrict__ partial, float* __restrict__ out) {
  const int t = threadIdx.x;
  float v = partial[t] + partial[t + 256];
#pragma unroll
  for (int d = 1; d < 64; d <<= 1) v += __shfl_xor(v, d);
  __shared__ float red[4];
  if ((t & 63) == 0) red[t >> 6] = v;
  __syncthreads();
  if (t == 0)
    out[0] = (red[0] + red[1] + red[2] + red[3]) * (1.0f / (float)(NB * (NT - 1)));
}

extern "C" void kernel_launch(void* const* d_in, const int* in_sizes, int n_in,
                              void* d_out, int out_size, void* d_ws, size_t ws_size,
                              hipStream_t stream) {
  (void)in_sizes; (void)n_in; (void)out_size; (void)ws_size;
  const float* x = (const float*)d_in[0];
  float* out = (float*)d_out;
  float* partial = (float*)d_ws;   // 2 KiB

  hipLaunchKernelGGL(fused_kernel, dim3(NB / 2), dim3(1024), 0, stream, x, partial);
  hipLaunchKernelGGL(reduce_kernel, dim3(1), dim3(256), 0, stream, partial, out);
}